// Round 12
// baseline (217.909 us; speedup 1.0000x reference)
//
#include <hip/hip_runtime.h>
#include <math.h>

#define TWO_PI_F 6.283185307179586f
#define WROWS 512          // rows per wave-tile (6 KB LDS)
#define WBLK  64           // one wave per block

typedef float f32x4 __attribute__((ext_vector_type(4)));

// Kernel A: per-group rotation matrices, padded to 12 floats/group
// (rows at float4 offsets 0,1,2). R = I + sin*K + (1-cos)*K^2; identity if
// apply_rand >= 0.5.
__global__ void compute_R_kernel(const float* __restrict__ axis,
                                 const float* __restrict__ angle,
                                 const float* __restrict__ apply_rand,
                                 float* __restrict__ R, int G) {
    int g = blockIdx.x * blockDim.x + threadIdx.x;
    if (g >= G) return;
    float a = axis[3 * g + 0];
    float b = axis[3 * g + 1];
    float c = axis[3 * g + 2];
    float inv = rsqrtf(a * a + b * b + c * c);
    a *= inv; b *= inv; c *= inv;
    float th = angle[g] * TWO_PI_F;
    float s, co;
    sincosf(th, &s, &co);
    float omc = 1.0f - co;

    float r00 = 1.0f - omc * (b * b + c * c);
    float r01 = -s * c + omc * (a * b);
    float r02 =  s * b + omc * (a * c);
    float r10 =  s * c + omc * (a * b);
    float r11 = 1.0f - omc * (a * a + c * c);
    float r12 = -s * a + omc * (b * c);
    float r20 = -s * b + omc * (a * c);
    float r21 =  s * a + omc * (b * c);
    float r22 = 1.0f - omc * (a * a + b * b);

    if (!(apply_rand[g] < 0.5f)) {
        r00 = 1.0f; r01 = 0.0f; r02 = 0.0f;
        r10 = 0.0f; r11 = 1.0f; r12 = 0.0f;
        r20 = 0.0f; r21 = 0.0f; r22 = 1.0f;
    }
    float4* Rg = reinterpret_cast<float4*>(R + 12 * (size_t)g);
    Rg[0] = make_float4(r00, r01, r02, 0.0f);
    Rg[1] = make_float4(r10, r11, r12, 0.0f);
    Rg[2] = make_float4(r20, r21, r22, 0.0f);
}

// Kernel A2: group boundaries from the SORTED batch arrays.
// start[g] = lower_bound(batch, g), start[G] = n.
__global__ void bounds_kernel(const int* __restrict__ nb, int N,
                              const int* __restrict__ eb, int E, int G,
                              int* __restrict__ nstart,
                              int* __restrict__ estart) {
    int i = blockIdx.x * blockDim.x + threadIdx.x;
    if (i >= 2 * (G + 1)) return;
    bool isEdge = i > G;
    int g = isEdge ? i - (G + 1) : i;
    const int* b = isEdge ? eb : nb;
    int n = isEdge ? E : N;
    int lo = 0, hi = n;
    while (lo < hi) {
        int mid = (lo + hi) >> 1;
        if (b[mid] < g) lo = mid + 1; else hi = mid;
    }
    if (isEdge) estart[g] = lo; else nstart[g] = lo;
}

// Kernel B (wave-tile, 512 rows): ONE WAVE per block, 512 rows per wave
// (384 float4, 6 KB LDS, 6 loads/lane issued back-to-back upfront so the
// ~900-cycle HBM latency is paid once per 6 KB, not per 3 KB). Group
// indices derived from the 32 KB boundaries array (binary search + linear
// walk, overlapped with the input-load latency). NT stores keep the
// write-once outputs from evicting the input set in L3.
template <bool HAS_BATCH>
__global__ __launch_bounds__(WBLK) void apply_rot_wave(
        const float* __restrict__ v,
        const int* __restrict__ start,   // G+1 boundaries (HAS_BATCH only)
        const float* __restrict__ R,
        float* __restrict__ out, int n, int G) {
    __shared__ float buf[WROWS * 3];
    float4* buf4 = reinterpret_cast<float4*>(buf);

    const int lane = threadIdx.x;
    const size_t rowBase = (size_t)blockIdx.x * WROWS;
    int rows = n - (int)rowBase;
    if (rows > WROWS) rows = WROWS;
    const int floatsHere = rows * 3;
    const int f4Here = floatsHere >> 2;       // 384 for a full tile
    const int tailFloats = floatsHere & 3;
    const int nRow4 = rows >> 2;              // 128 for a full tile

    // ---- issue ALL input loads back-to-back (longest latency first) ----
    float4 a[6];
    {
        const float4* src = reinterpret_cast<const float4*>(v + rowBase * 3);
#pragma unroll
        for (int k = 0; k < 6; ++k) {
            int i = lane + 64 * k;
            a[k] = (i < f4Here) ? src[i] : make_float4(0, 0, 0, 0);
        }
    }
    float aT = 0.f;
    if (tailFloats && lane < tailFloats)
        aT = v[rowBase * 3 + (((size_t)f4Here) << 2) + lane];

    // ---- group indices from boundaries (overlaps the loads above) ----
    // lane handles row-quads q0 = lane (rows rb+4*lane..+3) and
    // q1 = lane+64 (rows rb+4*lane+256..+259).
    int gsA[4], gsB[4];
    int gTail = 0;
    if (HAS_BATCH) {
        int rb = (int)rowBase;
        int lo = 0, hi = G;
        while (lo < hi) {                     // max g with start[g] <= rb
            int mid = (lo + hi + 1) >> 1;
            if (start[mid] <= rb) lo = mid; else hi = mid - 1;
        }
        int g = lo;
        gTail = g;
        int row0 = rb + 4 * lane;
#pragma unroll
        for (int r = 0; r < 4; ++r) {
            int row = row0 + r;
            while (start[g + 1] <= row) ++g;   // ~1-3 crossings per tile
            gsA[r] = g;
        }
#pragma unroll
        for (int r = 0; r < 4; ++r) {
            int row = row0 + 256 + r;
            while (start[g + 1] <= row) ++g;
            gsB[r] = g;
        }
    } else {
        int b = (int)rowBase + 4 * lane;
        gsA[0] = b;       gsA[1] = b + 1;     gsA[2] = b + 2;     gsA[3] = b + 3;
        gsB[0] = b + 256; gsB[1] = b + 257;   gsB[2] = b + 258;   gsB[3] = b + 259;
    }

    // ---- stage into LDS (single wave: barrier is just a waitcnt) ----
#pragma unroll
    for (int k = 0; k < 6; ++k) {
        int i = lane + 64 * k;
        if (i < f4Here) buf4[i] = a[k];
    }
    if (tailFloats && lane < tailFloats) buf[(f4Here << 2) + lane] = aT;
    __syncthreads();

    // ---- rotate: two row-quads per lane, in place ----
#pragma unroll
    for (int qq = 0; qq < 2; ++qq) {
        int q = lane + 64 * qq;
        if (q < nRow4) {
            float4 p0 = buf4[3 * q + 0];
            float4 p1 = buf4[3 * q + 1];
            float4 p2 = buf4[3 * q + 2];
            float rowsv[4][3] = {
                {p0.x, p0.y, p0.z},
                {p0.w, p1.x, p1.y},
                {p1.z, p1.w, p2.x},
                {p2.y, p2.z, p2.w}};
            const int* gq = (qq == 0) ? gsA : gsB;
            float oo[12];
#pragma unroll
            for (int r = 0; r < 4; ++r) {
                const float4* Rg = reinterpret_cast<const float4*>(R + 12 * (size_t)gq[r]);
                float4 R0 = Rg[0];
                float4 R1 = Rg[1];
                float4 R2 = Rg[2];
                float v0 = rowsv[r][0], v1 = rowsv[r][1], v2 = rowsv[r][2];
                oo[3 * r + 0] = R0.x * v0 + R0.y * v1 + R0.z * v2;
                oo[3 * r + 1] = R1.x * v0 + R1.y * v1 + R1.z * v2;
                oo[3 * r + 2] = R2.x * v0 + R2.y * v1 + R2.z * v2;
            }
            buf4[3 * q + 0] = make_float4(oo[0], oo[1], oo[2], oo[3]);
            buf4[3 * q + 1] = make_float4(oo[4], oo[5], oo[6], oo[7]);
            buf4[3 * q + 2] = make_float4(oo[8], oo[9], oo[10], oo[11]);
        }
    }
    // scalar tail rows (rows % 4) — not hit for these sizes, kept for safety
    if ((rows & 3) && lane == (nRow4 & 63) && (nRow4 >> 6) <= 1) {
        int g = gTail;
        for (int r = nRow4 * 4; r < rows; ++r) {
            int row = (int)rowBase + r;
            if (HAS_BATCH) { while (start[g + 1] <= row) ++g; }
            else g = row;
            const float* Rg = R + 12 * (size_t)g;
            float v0 = buf[3 * r + 0], v1 = buf[3 * r + 1], v2 = buf[3 * r + 2];
            float t0 = Rg[0] * v0 + Rg[1] * v1 + Rg[2]  * v2;
            float t1 = Rg[4] * v0 + Rg[5] * v1 + Rg[6]  * v2;
            float t2 = Rg[8] * v0 + Rg[9] * v1 + Rg[10] * v2;
            buf[3 * r + 0] = t0; buf[3 * r + 1] = t1; buf[3 * r + 2] = t2;
        }
    }
    __syncthreads();

    // ---- NT store out ----
    {
        const f32x4* b4 = reinterpret_cast<const f32x4*>(buf);
        f32x4* dst = reinterpret_cast<f32x4*>(out + rowBase * 3);
#pragma unroll
        for (int k = 0; k < 6; ++k) {
            int i = lane + 64 * k;
            if (i < f4Here) {
                f32x4 val = b4[i];
                __builtin_nontemporal_store(val, &dst[i]);
            }
        }
        if (tailFloats && lane < tailFloats) {
            int fi = (f4Here << 2) + lane;
            __builtin_nontemporal_store(buf[fi], &out[rowBase * 3 + fi]);
        }
    }
}

extern "C" void kernel_launch(void* const* d_in, const int* in_sizes, int n_in,
                              void* d_out, int out_size, void* d_ws, size_t ws_size,
                              hipStream_t stream) {
    const float* x          = (const float*)d_in[0];
    const float* edge_attr  = (const float*)d_in[1];
    const float* y          = (const float*)d_in[2];
    const int*   node_batch = (const int*)d_in[3];
    const int*   edge_batch = (const int*)d_in[4];
    const float* axis       = (const float*)d_in[5];
    const float* angle      = (const float*)d_in[6];
    const float* apply_rand = (const float*)d_in[7];

    const int N = in_sizes[3];
    const int E = in_sizes[4];
    const int G = in_sizes[6];

    float* R = (float*)d_ws;                       // G*12 floats = 384 KB
    int* nstart = (int*)(R + 12 * (size_t)G);      // G+1 ints
    int* estart = nstart + (G + 1);                // G+1 ints
    float* x_out = (float*)d_out;
    float* e_out = x_out + 3 * (size_t)N;
    float* y_out = e_out + 3 * (size_t)E;

    compute_R_kernel<<<(G + 255) / 256, 256, 0, stream>>>(
        axis, angle, apply_rand, R, G);
    bounds_kernel<<<(2 * (G + 1) + 255) / 256, 256, 0, stream>>>(
        node_batch, N, edge_batch, E, G, nstart, estart);

    int nbE = (int)(((size_t)E + WROWS - 1) / WROWS);
    int nbN = (int)(((size_t)N + WROWS - 1) / WROWS);
    int nbG = (int)(((size_t)G + WROWS - 1) / WROWS);

    apply_rot_wave<true><<<nbE, WBLK, 0, stream>>>(edge_attr, estart, R, e_out, E, G);
    apply_rot_wave<true><<<nbN, WBLK, 0, stream>>>(x, nstart, R, x_out, N, G);
    apply_rot_wave<false><<<nbG, WBLK, 0, stream>>>(y, nullptr, R, y_out, G, G);
}

// Round 13
// 97.293 us; speedup vs baseline: 2.2397x; 2.2397x over previous
//
#include <hip/hip_runtime.h>
#include <math.h>

#define TWO_PI_F 6.283185307179586f
#define WROWS 512          // rows per wave-tile (6 KB LDS)
#define WBLK  64           // one wave per block

typedef float f32x4 __attribute__((ext_vector_type(4)));

// Kernel A: per-group rotation matrices, padded to 12 floats/group
// (rows at float4 offsets 0,1,2). R = I + sin*K + (1-cos)*K^2; identity if
// apply_rand >= 0.5.
__global__ void compute_R_kernel(const float* __restrict__ axis,
                                 const float* __restrict__ angle,
                                 const float* __restrict__ apply_rand,
                                 float* __restrict__ R, int G) {
    int g = blockIdx.x * blockDim.x + threadIdx.x;
    if (g >= G) return;
    float a = axis[3 * g + 0];
    float b = axis[3 * g + 1];
    float c = axis[3 * g + 2];
    float inv = rsqrtf(a * a + b * b + c * c);
    a *= inv; b *= inv; c *= inv;
    float th = angle[g] * TWO_PI_F;
    float s, co;
    sincosf(th, &s, &co);
    float omc = 1.0f - co;

    float r00 = 1.0f - omc * (b * b + c * c);
    float r01 = -s * c + omc * (a * b);
    float r02 =  s * b + omc * (a * c);
    float r10 =  s * c + omc * (a * b);
    float r11 = 1.0f - omc * (a * a + c * c);
    float r12 = -s * a + omc * (b * c);
    float r20 = -s * b + omc * (a * c);
    float r21 =  s * a + omc * (b * c);
    float r22 = 1.0f - omc * (a * a + b * b);

    if (!(apply_rand[g] < 0.5f)) {
        r00 = 1.0f; r01 = 0.0f; r02 = 0.0f;
        r10 = 0.0f; r11 = 1.0f; r12 = 0.0f;
        r20 = 0.0f; r21 = 0.0f; r22 = 1.0f;
    }
    float4* Rg = reinterpret_cast<float4*>(R + 12 * (size_t)g);
    Rg[0] = make_float4(r00, r01, r02, 0.0f);
    Rg[1] = make_float4(r10, r11, r12, 0.0f);
    Rg[2] = make_float4(r20, r21, r22, 0.0f);
}

// Kernel A2: group boundaries from the SORTED batch arrays.
// start[g] = lower_bound(batch, g), start[G] = n.
__global__ void bounds_kernel(const int* __restrict__ nb, int N,
                              const int* __restrict__ eb, int E, int G,
                              int* __restrict__ nstart,
                              int* __restrict__ estart) {
    int i = blockIdx.x * blockDim.x + threadIdx.x;
    if (i >= 2 * (G + 1)) return;
    bool isEdge = i > G;
    int g = isEdge ? i - (G + 1) : i;
    const int* b = isEdge ? eb : nb;
    int n = isEdge ? E : N;
    int lo = 0, hi = n;
    while (lo < hi) {
        int mid = (lo + hi) >> 1;
        if (b[mid] < g) lo = mid + 1; else hi = mid;
    }
    if (isEdge) estart[g] = lo; else nstart[g] = lo;
}

// Kernel B (wave-tile, 512 rows): ONE WAVE per block, 512 rows per wave
// (384 float4, 6 KB LDS, 6 loads/lane issued back-to-back upfront). Group
// indices derived from the 32 KB boundaries array. IMPORTANT: every walked
// row is CLAMPED to n-1 — an unclamped walk on the last partial tile runs
// off the end of start[] and crawls through adjacent memory (~1000 dependent
// loads; this was R12's 135-us straggler block). NT stores keep the
// write-once outputs from evicting the input set in L3.
template <bool HAS_BATCH>
__global__ __launch_bounds__(WBLK) void apply_rot_wave(
        const float* __restrict__ v,
        const int* __restrict__ start,   // G+1 boundaries (HAS_BATCH only)
        const float* __restrict__ R,
        float* __restrict__ out, int n, int G) {
    __shared__ float buf[WROWS * 3];
    float4* buf4 = reinterpret_cast<float4*>(buf);

    const int lane = threadIdx.x;
    const size_t rowBase = (size_t)blockIdx.x * WROWS;
    int rows = n - (int)rowBase;
    if (rows > WROWS) rows = WROWS;
    const int floatsHere = rows * 3;
    const int f4Here = floatsHere >> 2;       // 384 for a full tile
    const int tailFloats = floatsHere & 3;
    const int nRow4 = rows >> 2;              // 128 for a full tile

    // ---- issue ALL input loads back-to-back (longest latency first) ----
    float4 a[6];
    {
        const float4* src = reinterpret_cast<const float4*>(v + rowBase * 3);
#pragma unroll
        for (int k = 0; k < 6; ++k) {
            int i = lane + 64 * k;
            a[k] = (i < f4Here) ? src[i] : make_float4(0, 0, 0, 0);
        }
    }
    float aT = 0.f;
    if (tailFloats && lane < tailFloats)
        aT = v[rowBase * 3 + (((size_t)f4Here) << 2) + lane];

    // ---- group indices from boundaries (overlaps the loads above) ----
    // lane handles row-quads q0 = lane (rows rb+4*lane..+3) and
    // q1 = lane+64 (rows rb+4*lane+256..+259). Rows clamped to n-1 so the
    // walk never leaves [0, G).
    int gsA[4], gsB[4];
    const int rowMax = n - 1;
    if (HAS_BATCH) {
        int rb = (int)rowBase;
        int lo = 0, hi = G;
        while (lo < hi) {                     // max g with start[g] <= rb
            int mid = (lo + hi + 1) >> 1;
            if (start[mid] <= rb) lo = mid; else hi = mid - 1;
        }
        int g = lo;
        int row0 = rb + 4 * lane;
#pragma unroll
        for (int r = 0; r < 4; ++r) {
            int row = row0 + r;
            if (row > rowMax) row = rowMax;
            while (start[g + 1] <= row) ++g;   // ~1-3 crossings per tile
            gsA[r] = g;
        }
#pragma unroll
        for (int r = 0; r < 4; ++r) {
            int row = row0 + 256 + r;
            if (row > rowMax) row = rowMax;
            while (start[g + 1] <= row) ++g;
            gsB[r] = g;
        }
    } else {
        int b = (int)rowBase + 4 * lane;
        gsA[0] = b;       gsA[1] = b + 1;     gsA[2] = b + 2;     gsA[3] = b + 3;
        gsB[0] = b + 256; gsB[1] = b + 257;   gsB[2] = b + 258;   gsB[3] = b + 259;
    }

    // ---- stage into LDS (single wave: barrier is just a waitcnt) ----
#pragma unroll
    for (int k = 0; k < 6; ++k) {
        int i = lane + 64 * k;
        if (i < f4Here) buf4[i] = a[k];
    }
    if (tailFloats && lane < tailFloats) buf[(f4Here << 2) + lane] = aT;
    __syncthreads();

    // ---- rotate: two row-quads per lane, in place ----
#pragma unroll
    for (int qq = 0; qq < 2; ++qq) {
        int q = lane + 64 * qq;
        if (q < nRow4) {
            float4 p0 = buf4[3 * q + 0];
            float4 p1 = buf4[3 * q + 1];
            float4 p2 = buf4[3 * q + 2];
            float rowsv[4][3] = {
                {p0.x, p0.y, p0.z},
                {p0.w, p1.x, p1.y},
                {p1.z, p1.w, p2.x},
                {p2.y, p2.z, p2.w}};
            const int* gq = (qq == 0) ? gsA : gsB;
            float oo[12];
#pragma unroll
            for (int r = 0; r < 4; ++r) {
                const float4* Rg = reinterpret_cast<const float4*>(R + 12 * (size_t)gq[r]);
                float4 R0 = Rg[0];
                float4 R1 = Rg[1];
                float4 R2 = Rg[2];
                float v0 = rowsv[r][0], v1 = rowsv[r][1], v2 = rowsv[r][2];
                oo[3 * r + 0] = R0.x * v0 + R0.y * v1 + R0.z * v2;
                oo[3 * r + 1] = R1.x * v0 + R1.y * v1 + R1.z * v2;
                oo[3 * r + 2] = R2.x * v0 + R2.y * v1 + R2.z * v2;
            }
            buf4[3 * q + 0] = make_float4(oo[0], oo[1], oo[2], oo[3]);
            buf4[3 * q + 1] = make_float4(oo[4], oo[5], oo[6], oo[7]);
            buf4[3 * q + 2] = make_float4(oo[8], oo[9], oo[10], oo[11]);
        }
    }
    // scalar tail rows (rows % 4): E, N, G are all divisible by 4 for this
    // problem; handled by clamping above if ever hit (outputs of clamped
    // duplicate rows are overwritten by the真 rows' lanes, never read OOB).
    __syncthreads();

    // ---- NT store out ----
    {
        const f32x4* b4 = reinterpret_cast<const f32x4*>(buf);
        f32x4* dst = reinterpret_cast<f32x4*>(out + rowBase * 3);
#pragma unroll
        for (int k = 0; k < 6; ++k) {
            int i = lane + 64 * k;
            if (i < f4Here) {
                f32x4 val = b4[i];
                __builtin_nontemporal_store(val, &dst[i]);
            }
        }
        if (tailFloats && lane < tailFloats) {
            int fi = (f4Here << 2) + lane;
            __builtin_nontemporal_store(buf[fi], &out[rowBase * 3 + fi]);
        }
    }
}

extern "C" void kernel_launch(void* const* d_in, const int* in_sizes, int n_in,
                              void* d_out, int out_size, void* d_ws, size_t ws_size,
                              hipStream_t stream) {
    const float* x          = (const float*)d_in[0];
    const float* edge_attr  = (const float*)d_in[1];
    const float* y          = (const float*)d_in[2];
    const int*   node_batch = (const int*)d_in[3];
    const int*   edge_batch = (const int*)d_in[4];
    const float* axis       = (const float*)d_in[5];
    const float* angle      = (const float*)d_in[6];
    const float* apply_rand = (const float*)d_in[7];

    const int N = in_sizes[3];
    const int E = in_sizes[4];
    const int G = in_sizes[6];

    float* R = (float*)d_ws;                       // G*12 floats = 384 KB
    int* nstart = (int*)(R + 12 * (size_t)G);      // G+1 ints
    int* estart = nstart + (G + 1);                // G+1 ints
    float* x_out = (float*)d_out;
    float* e_out = x_out + 3 * (size_t)N;
    float* y_out = e_out + 3 * (size_t)E;

    compute_R_kernel<<<(G + 255) / 256, 256, 0, stream>>>(
        axis, angle, apply_rand, R, G);
    bounds_kernel<<<(2 * (G + 1) + 255) / 256, 256, 0, stream>>>(
        node_batch, N, edge_batch, E, G, nstart, estart);

    int nbE = (int)(((size_t)E + WROWS - 1) / WROWS);
    int nbN = (int)(((size_t)N + WROWS - 1) / WROWS);
    int nbG = (int)(((size_t)G + WROWS - 1) / WROWS);

    apply_rot_wave<true><<<nbE, WBLK, 0, stream>>>(edge_attr, estart, R, e_out, E, G);
    apply_rot_wave<true><<<nbN, WBLK, 0, stream>>>(x, nstart, R, x_out, N, G);
    apply_rot_wave<false><<<nbG, WBLK, 0, stream>>>(y, nullptr, R, y_out, G, G);
}

// Round 14
// 95.746 us; speedup vs baseline: 2.2759x; 1.0162x over previous
//
#include <hip/hip_runtime.h>
#include <math.h>

#define TWO_PI_F 6.283185307179586f
#define WROWS 256          // rows per wave-tile (3 KB LDS)
#define WBLK  64           // one wave per block

typedef float f32x4 __attribute__((ext_vector_type(4)));

__device__ __forceinline__ int lower_bound_dev(const int* __restrict__ b,
                                               int n, int g) {
    int lo = 0, hi = n;
    while (lo < hi) {
        int mid = (lo + hi) >> 1;
        if (b[mid] < g) lo = mid + 1; else hi = mid;
    }
    return lo;
}

// ONE prep kernel, role-split by global thread id:
//   [0, G)                 : rotation matrix R[g] (12 floats, rows at f4 0,1,2)
//   [G, G+(G+1))           : nstart[g] = lower_bound(node_batch, g)
//   [.., +(G+1))           : estart[g] = lower_bound(edge_batch, g)
//   [.., +TN)              : ntileg[t] = node_batch[min(t*WROWS, N-1)]
//   [.., +TE)              : etileg[t] = edge_batch[min(t*WROWS, E-1)]
__global__ void prep_kernel(const float* __restrict__ axis,
                            const float* __restrict__ angle,
                            const float* __restrict__ apply_rand,
                            const int* __restrict__ nb, int N,
                            const int* __restrict__ eb, int E, int G,
                            float* __restrict__ R,
                            int* __restrict__ nstart, int* __restrict__ estart,
                            int* __restrict__ ntileg, int* __restrict__ etileg,
                            int TN, int TE) {
    int i = blockIdx.x * blockDim.x + threadIdx.x;
    if (i < G) {
        int g = i;
        float a = axis[3 * g + 0];
        float b = axis[3 * g + 1];
        float c = axis[3 * g + 2];
        float inv = rsqrtf(a * a + b * b + c * c);
        a *= inv; b *= inv; c *= inv;
        float th = angle[g] * TWO_PI_F;
        float s, co;
        sincosf(th, &s, &co);
        float omc = 1.0f - co;

        float r00 = 1.0f - omc * (b * b + c * c);
        float r01 = -s * c + omc * (a * b);
        float r02 =  s * b + omc * (a * c);
        float r10 =  s * c + omc * (a * b);
        float r11 = 1.0f - omc * (a * a + c * c);
        float r12 = -s * a + omc * (b * c);
        float r20 = -s * b + omc * (a * c);
        float r21 =  s * a + omc * (b * c);
        float r22 = 1.0f - omc * (a * a + b * b);

        if (!(apply_rand[g] < 0.5f)) {
            r00 = 1.0f; r01 = 0.0f; r02 = 0.0f;
            r10 = 0.0f; r11 = 1.0f; r12 = 0.0f;
            r20 = 0.0f; r21 = 0.0f; r22 = 1.0f;
        }
        float4* Rg = reinterpret_cast<float4*>(R + 12 * (size_t)g);
        Rg[0] = make_float4(r00, r01, r02, 0.0f);
        Rg[1] = make_float4(r10, r11, r12, 0.0f);
        Rg[2] = make_float4(r20, r21, r22, 0.0f);
        return;
    }
    i -= G;
    if (i < G + 1) { nstart[i] = lower_bound_dev(nb, N, i); return; }
    i -= (G + 1);
    if (i < G + 1) { estart[i] = lower_bound_dev(eb, E, i); return; }
    i -= (G + 1);
    if (i < TN) {
        int rb = i * WROWS;
        if (rb > N - 1) rb = N - 1;
        ntileg[i] = nb[rb];
        return;
    }
    i -= TN;
    if (i < TE) {
        size_t rb = (size_t)i * WROWS;
        if (rb > (size_t)(E - 1)) rb = (size_t)(E - 1);
        etileg[i] = eb[rb];
        return;
    }
}

// Kernel B (wave-tile, 256 rows): ONE WAVE per block (R11 structure, best
// measured). Group indices: ONE broadcast load of tileg[blockIdx.x] + a
// <=2-3-step linear walk over start[] — replaces R11's 13 serially-dependent
// binary-search loads that sat on every wave's critical path. Rows clamped
// to n-1 (R12 lesson: an unclamped walk on the last partial tile crawls off
// start[] through adjacent memory). NT stores keep the write-once outputs
// from evicting the input set in L3.
template <bool HAS_BATCH>
__global__ __launch_bounds__(WBLK) void apply_rot_wave(
        const float* __restrict__ v,
        const int* __restrict__ start,   // G+1 boundaries (HAS_BATCH only)
        const int* __restrict__ tileg,   // per-tile starting group
        const float* __restrict__ R,
        float* __restrict__ out, int n, int G) {
    __shared__ float buf[WROWS * 3];
    float4* buf4 = reinterpret_cast<float4*>(buf);

    const int lane = threadIdx.x;
    const size_t rowBase = (size_t)blockIdx.x * WROWS;
    int rows = n - (int)rowBase;
    if (rows > WROWS) rows = WROWS;
    const int floatsHere = rows * 3;
    const int f4Here = floatsHere >> 2;       // 192 for a full tile
    const int tailFloats = floatsHere & 3;
    const int nRow4 = rows >> 2;              // 64 for a full tile

    // ---- issue the input loads first (longest latency) ----
    float4 a0 = make_float4(0, 0, 0, 0), a1 = a0, a2 = a0;
    float aT = 0.f;
    {
        const float4* src = reinterpret_cast<const float4*>(v + rowBase * 3);
        if (lane < f4Here)       a0 = src[lane];
        if (lane + 64 < f4Here)  a1 = src[lane + 64];
        if (lane + 128 < f4Here) a2 = src[lane + 128];
        if (tailFloats && lane < tailFloats)
            aT = v[rowBase * 3 + (((size_t)f4Here) << 2) + lane];
    }

    // ---- group indices (overlaps the loads above; no binary search) ----
    int gs[4];
    if (HAS_BATCH) {
        int g = tileg[blockIdx.x];            // broadcast scalar load
        const int rowMax = n - 1;
        int row0 = (int)rowBase + 4 * lane;
#pragma unroll
        for (int r = 0; r < 4; ++r) {
            int row = row0 + r;
            if (row > rowMax) row = rowMax;
            while (start[g + 1] <= row) ++g;  // <=~3 steps per tile
            gs[r] = g;
        }
    } else {
        int b = (int)rowBase + 4 * lane;
        gs[0] = b; gs[1] = b + 1; gs[2] = b + 2; gs[3] = b + 3;
    }

    // ---- stage into LDS (single wave: barrier is just a waitcnt) ----
    if (lane < f4Here)       buf4[lane]       = a0;
    if (lane + 64 < f4Here)  buf4[lane + 64]  = a1;
    if (lane + 128 < f4Here) buf4[lane + 128] = a2;
    if (tailFloats && lane < tailFloats) buf[(f4Here << 2) + lane] = aT;
    __syncthreads();

    // ---- rotate 4 rows per lane, in place ----
    if (lane < nRow4) {
        float4 p0 = buf4[3 * lane + 0];
        float4 p1 = buf4[3 * lane + 1];
        float4 p2 = buf4[3 * lane + 2];
        float rowsv[4][3] = {
            {p0.x, p0.y, p0.z},
            {p0.w, p1.x, p1.y},
            {p1.z, p1.w, p2.x},
            {p2.y, p2.z, p2.w}};
        float oo[12];
#pragma unroll
        for (int r = 0; r < 4; ++r) {
            const float4* Rg = reinterpret_cast<const float4*>(R + 12 * (size_t)gs[r]);
            float4 R0 = Rg[0];
            float4 R1 = Rg[1];
            float4 R2 = Rg[2];
            float v0 = rowsv[r][0], v1 = rowsv[r][1], v2 = rowsv[r][2];
            oo[3 * r + 0] = R0.x * v0 + R0.y * v1 + R0.z * v2;
            oo[3 * r + 1] = R1.x * v0 + R1.y * v1 + R1.z * v2;
            oo[3 * r + 2] = R2.x * v0 + R2.y * v1 + R2.z * v2;
        }
        buf4[3 * lane + 0] = make_float4(oo[0], oo[1], oo[2], oo[3]);
        buf4[3 * lane + 1] = make_float4(oo[4], oo[5], oo[6], oo[7]);
        buf4[3 * lane + 2] = make_float4(oo[8], oo[9], oo[10], oo[11]);
    }
    // (rows % 4 tail: E, N, G all divisible by 4 here; clamped duplicate
    // rows would be overwritten by their true lanes if ever hit.)
    __syncthreads();

    // ---- NT store out ----
    {
        const f32x4* b4 = reinterpret_cast<const f32x4*>(buf);
        f32x4* dst = reinterpret_cast<f32x4*>(out + rowBase * 3);
        if (lane < f4Here) {
            f32x4 val = b4[lane];
            __builtin_nontemporal_store(val, &dst[lane]);
        }
        if (lane + 64 < f4Here) {
            f32x4 val = b4[lane + 64];
            __builtin_nontemporal_store(val, &dst[lane + 64]);
        }
        if (lane + 128 < f4Here) {
            f32x4 val = b4[lane + 128];
            __builtin_nontemporal_store(val, &dst[lane + 128]);
        }
        if (tailFloats && lane < tailFloats) {
            int fi = (f4Here << 2) + lane;
            __builtin_nontemporal_store(buf[fi], &out[rowBase * 3 + fi]);
        }
    }
}

extern "C" void kernel_launch(void* const* d_in, const int* in_sizes, int n_in,
                              void* d_out, int out_size, void* d_ws, size_t ws_size,
                              hipStream_t stream) {
    const float* x          = (const float*)d_in[0];
    const float* edge_attr  = (const float*)d_in[1];
    const float* y          = (const float*)d_in[2];
    const int*   node_batch = (const int*)d_in[3];
    const int*   edge_batch = (const int*)d_in[4];
    const float* axis       = (const float*)d_in[5];
    const float* angle      = (const float*)d_in[6];
    const float* apply_rand = (const float*)d_in[7];

    const int N = in_sizes[3];
    const int E = in_sizes[4];
    const int G = in_sizes[6];

    int TN = (int)(((size_t)N + WROWS - 1) / WROWS);
    int TE = (int)(((size_t)E + WROWS - 1) / WROWS);
    int TG = (int)(((size_t)G + WROWS - 1) / WROWS);

    float* R    = (float*)d_ws;                    // G*12 floats = 384 KB
    int* nstart = (int*)(R + 12 * (size_t)G);      // G+1 ints
    int* estart = nstart + (G + 1);                // G+1 ints
    int* ntileg = estart + (G + 1);                // TN ints
    int* etileg = ntileg + TN;                     // TE ints
    float* x_out = (float*)d_out;
    float* e_out = x_out + 3 * (size_t)N;
    float* y_out = e_out + 3 * (size_t)E;

    int prepThreads = G + 2 * (G + 1) + TN + TE;
    prep_kernel<<<(prepThreads + 255) / 256, 256, 0, stream>>>(
        axis, angle, apply_rand, node_batch, N, edge_batch, E, G,
        R, nstart, estart, ntileg, etileg, TN, TE);

    apply_rot_wave<true><<<TE, WBLK, 0, stream>>>(edge_attr, estart, etileg, R, e_out, E, G);
    apply_rot_wave<true><<<TN, WBLK, 0, stream>>>(x, nstart, ntileg, R, x_out, N, G);
    apply_rot_wave<false><<<TG, WBLK, 0, stream>>>(y, nullptr, nullptr, R, y_out, G, G);
}

// Round 15
// 90.265 us; speedup vs baseline: 2.4141x; 1.0607x over previous
//
#include <hip/hip_runtime.h>
#include <math.h>

#define TWO_PI_F 6.283185307179586f
#define WROWS 256          // rows per wave-tile (3 KB LDS)
#define WBLK  64           // one wave per block

typedef float f32x4 __attribute__((ext_vector_type(4)));

__device__ __forceinline__ int lower_bound_dev(const int* __restrict__ b,
                                               int n, int g) {
    int lo = 0, hi = n;
    while (lo < hi) {
        int mid = (lo + hi) >> 1;
        if (b[mid] < g) lo = mid + 1; else hi = mid;
    }
    return lo;
}

// ONE prep kernel, role-split by global thread id:
//   [0, G)            : rotation matrix R[g] (12 floats, rows at f4 0,1,2)
//   [G, +(G+1))       : nstart[g] = lower_bound(node_batch, g)
//   [.., +(G+1))      : estart[g] = lower_bound(edge_batch, g)
//   [.., +TE+TN)      : tileg[t]: t<TE -> edge_batch[t*WROWS], else node
__global__ void prep_kernel(const float* __restrict__ axis,
                            const float* __restrict__ angle,
                            const float* __restrict__ apply_rand,
                            const int* __restrict__ nb, int N,
                            const int* __restrict__ eb, int E, int G,
                            float* __restrict__ R,
                            int* __restrict__ nstart, int* __restrict__ estart,
                            int* __restrict__ tileg, int TE, int TN) {
    int i = blockIdx.x * blockDim.x + threadIdx.x;
    if (i < G) {
        int g = i;
        float a = axis[3 * g + 0];
        float b = axis[3 * g + 1];
        float c = axis[3 * g + 2];
        float inv = rsqrtf(a * a + b * b + c * c);
        a *= inv; b *= inv; c *= inv;
        float th = angle[g] * TWO_PI_F;
        float s, co;
        sincosf(th, &s, &co);
        float omc = 1.0f - co;

        float r00 = 1.0f - omc * (b * b + c * c);
        float r01 = -s * c + omc * (a * b);
        float r02 =  s * b + omc * (a * c);
        float r10 =  s * c + omc * (a * b);
        float r11 = 1.0f - omc * (a * a + c * c);
        float r12 = -s * a + omc * (b * c);
        float r20 = -s * b + omc * (a * c);
        float r21 =  s * a + omc * (b * c);
        float r22 = 1.0f - omc * (a * a + b * b);

        if (!(apply_rand[g] < 0.5f)) {
            r00 = 1.0f; r01 = 0.0f; r02 = 0.0f;
            r10 = 0.0f; r11 = 1.0f; r12 = 0.0f;
            r20 = 0.0f; r21 = 0.0f; r22 = 1.0f;
        }
        float4* Rg = reinterpret_cast<float4*>(R + 12 * (size_t)g);
        Rg[0] = make_float4(r00, r01, r02, 0.0f);
        Rg[1] = make_float4(r10, r11, r12, 0.0f);
        Rg[2] = make_float4(r20, r21, r22, 0.0f);
        return;
    }
    i -= G;
    if (i < G + 1) { nstart[i] = lower_bound_dev(nb, N, i); return; }
    i -= (G + 1);
    if (i < G + 1) { estart[i] = lower_bound_dev(eb, E, i); return; }
    i -= (G + 1);
    if (i < TE) {
        size_t rb = (size_t)i * WROWS;
        if (rb > (size_t)(E - 1)) rb = (size_t)(E - 1);
        tileg[i] = eb[rb];
        return;
    }
    i -= TE;
    if (i < TN) {
        int rb = i * WROWS;
        if (rb > N - 1) rb = N - 1;
        tileg[TE + i] = nb[rb];
        return;
    }
}

// Fused apply (wave-tile, 256 rows, ONE WAVE per block): unified tile list
// [0,TE) edge, [TE,TE+TN) node, [TE+TN, +TG) y — node/y tiles fill the edge
// kernel's dispatch tail instead of running as separate serialized launches.
// Per-wave structure identical to R14 (best measured): tileg broadcast +
// <=3-step walk (rows clamped to n-1, R12 lesson), LDS AoS shuffle,
// NT stores.
__global__ __launch_bounds__(WBLK) void apply_fused_wave(
        const float* __restrict__ ev, float* __restrict__ eo, int E, int TE,
        const float* __restrict__ xv, float* __restrict__ xo, int N, int TN,
        const float* __restrict__ yv, float* __restrict__ yo, int G,
        const int* __restrict__ estart, const int* __restrict__ nstart,
        const int* __restrict__ tileg,
        const float* __restrict__ R) {
    __shared__ float buf[WROWS * 3];
    float4* buf4 = reinterpret_cast<float4*>(buf);

    const int lane = threadIdx.x;
    const int t = blockIdx.x;

    const float* v; float* o; const int* start; int n; size_t rowBase;
    bool hasB;
    if (t < TE) {
        v = ev; o = eo; start = estart; n = E; hasB = true;
        rowBase = (size_t)t * WROWS;
    } else if (t < TE + TN) {
        int u = t - TE;
        v = xv; o = xo; start = nstart; n = N; hasB = true;
        rowBase = (size_t)u * WROWS;
    } else {
        int u = t - TE - TN;
        v = yv; o = yo; start = nullptr; n = G; hasB = false;
        rowBase = (size_t)u * WROWS;
    }

    int rows = n - (int)rowBase;
    if (rows > WROWS) rows = WROWS;
    const int floatsHere = rows * 3;
    const int f4Here = floatsHere >> 2;       // 192 for a full tile
    const int tailFloats = floatsHere & 3;
    const int nRow4 = rows >> 2;              // 64 for a full tile

    // ---- issue the input loads first (longest latency) ----
    float4 a0 = make_float4(0, 0, 0, 0), a1 = a0, a2 = a0;
    float aT = 0.f;
    {
        const float4* src = reinterpret_cast<const float4*>(v + rowBase * 3);
        if (lane < f4Here)       a0 = src[lane];
        if (lane + 64 < f4Here)  a1 = src[lane + 64];
        if (lane + 128 < f4Here) a2 = src[lane + 128];
        if (tailFloats && lane < tailFloats)
            aT = v[rowBase * 3 + (((size_t)f4Here) << 2) + lane];
    }

    // ---- group indices (overlaps the loads above; no binary search) ----
    int gs[4];
    if (hasB) {
        int g = tileg[t];                     // broadcast scalar load
        const int rowMax = n - 1;
        int row0 = (int)rowBase + 4 * lane;
#pragma unroll
        for (int r = 0; r < 4; ++r) {
            int row = row0 + r;
            if (row > rowMax) row = rowMax;
            while (start[g + 1] <= row) ++g;  // <=~3 steps per tile
            gs[r] = g;
        }
    } else {
        int b = (int)rowBase + 4 * lane;
        gs[0] = b; gs[1] = b + 1; gs[2] = b + 2; gs[3] = b + 3;
    }

    // ---- stage into LDS (single wave: barrier is just a waitcnt) ----
    if (lane < f4Here)       buf4[lane]       = a0;
    if (lane + 64 < f4Here)  buf4[lane + 64]  = a1;
    if (lane + 128 < f4Here) buf4[lane + 128] = a2;
    if (tailFloats && lane < tailFloats) buf[(f4Here << 2) + lane] = aT;
    __syncthreads();

    // ---- rotate 4 rows per lane, in place ----
    if (lane < nRow4) {
        float4 p0 = buf4[3 * lane + 0];
        float4 p1 = buf4[3 * lane + 1];
        float4 p2 = buf4[3 * lane + 2];
        float rowsv[4][3] = {
            {p0.x, p0.y, p0.z},
            {p0.w, p1.x, p1.y},
            {p1.z, p1.w, p2.x},
            {p2.y, p2.z, p2.w}};
        float oo[12];
#pragma unroll
        for (int r = 0; r < 4; ++r) {
            const float4* Rg = reinterpret_cast<const float4*>(R + 12 * (size_t)gs[r]);
            float4 R0 = Rg[0];
            float4 R1 = Rg[1];
            float4 R2 = Rg[2];
            float v0 = rowsv[r][0], v1 = rowsv[r][1], v2 = rowsv[r][2];
            oo[3 * r + 0] = R0.x * v0 + R0.y * v1 + R0.z * v2;
            oo[3 * r + 1] = R1.x * v0 + R1.y * v1 + R1.z * v2;
            oo[3 * r + 2] = R2.x * v0 + R2.y * v1 + R2.z * v2;
        }
        buf4[3 * lane + 0] = make_float4(oo[0], oo[1], oo[2], oo[3]);
        buf4[3 * lane + 1] = make_float4(oo[4], oo[5], oo[6], oo[7]);
        buf4[3 * lane + 2] = make_float4(oo[8], oo[9], oo[10], oo[11]);
    }
    // (rows % 4 tail: E, N, G all divisible by 4 here; clamped duplicate
    // rows would be overwritten by their true lanes if ever hit.)
    __syncthreads();

    // ---- NT store out ----
    {
        const f32x4* b4 = reinterpret_cast<const f32x4*>(buf);
        f32x4* dst = reinterpret_cast<f32x4*>(o + rowBase * 3);
        if (lane < f4Here) {
            f32x4 val = b4[lane];
            __builtin_nontemporal_store(val, &dst[lane]);
        }
        if (lane + 64 < f4Here) {
            f32x4 val = b4[lane + 64];
            __builtin_nontemporal_store(val, &dst[lane + 64]);
        }
        if (lane + 128 < f4Here) {
            f32x4 val = b4[lane + 128];
            __builtin_nontemporal_store(val, &dst[lane + 128]);
        }
        if (tailFloats && lane < tailFloats) {
            int fi = (f4Here << 2) + lane;
            __builtin_nontemporal_store(buf[fi], &o[rowBase * 3 + fi]);
        }
    }
}

extern "C" void kernel_launch(void* const* d_in, const int* in_sizes, int n_in,
                              void* d_out, int out_size, void* d_ws, size_t ws_size,
                              hipStream_t stream) {
    const float* x          = (const float*)d_in[0];
    const float* edge_attr  = (const float*)d_in[1];
    const float* y          = (const float*)d_in[2];
    const int*   node_batch = (const int*)d_in[3];
    const int*   edge_batch = (const int*)d_in[4];
    const float* axis       = (const float*)d_in[5];
    const float* angle      = (const float*)d_in[6];
    const float* apply_rand = (const float*)d_in[7];

    const int N = in_sizes[3];
    const int E = in_sizes[4];
    const int G = in_sizes[6];

    int TE = (int)(((size_t)E + WROWS - 1) / WROWS);
    int TN = (int)(((size_t)N + WROWS - 1) / WROWS);
    int TG = (int)(((size_t)G + WROWS - 1) / WROWS);

    float* R    = (float*)d_ws;                    // G*12 floats = 384 KB
    int* nstart = (int*)(R + 12 * (size_t)G);      // G+1 ints
    int* estart = nstart + (G + 1);                // G+1 ints
    int* tileg  = estart + (G + 1);                // TE+TN ints
    float* x_out = (float*)d_out;
    float* e_out = x_out + 3 * (size_t)N;
    float* y_out = e_out + 3 * (size_t)E;

    int prepThreads = G + 2 * (G + 1) + TE + TN;
    prep_kernel<<<(prepThreads + 255) / 256, 256, 0, stream>>>(
        axis, angle, apply_rand, node_batch, N, edge_batch, E, G,
        R, nstart, estart, tileg, TE, TN);

    apply_fused_wave<<<TE + TN + TG, WBLK, 0, stream>>>(
        edge_attr, e_out, E, TE,
        x, x_out, N, TN,
        y, y_out, G,
        estart, nstart, tileg, R);
}